// Round 13
// baseline (224.605 us; speedup 1.0000x reference)
//
#include <hip/hip_runtime.h>
#include <hip/hip_bf16.h>
#include <math.h>

typedef float  f32x4  __attribute__((ext_vector_type(4)));
typedef float  f32x16 __attribute__((ext_vector_type(16)));
typedef short  s16x8  __attribute__((ext_vector_type(8)));
typedef __bf16 bf16x8 __attribute__((ext_vector_type(8)));
typedef unsigned int u32;
typedef unsigned int u32x4 __attribute__((ext_vector_type(4)));
typedef unsigned short u16;
typedef unsigned long long u64;

#define DEVI static __device__ __forceinline__

#if defined(__has_builtin) && __has_builtin(__builtin_amdgcn_exp2f)
#define EXP2(x) __builtin_amdgcn_exp2f(x)
#else
#define EXP2(x) exp2f(x)
#endif

// one-instruction packed f32->bf16 RNE pair (v_cvt_pk_bf16_f32)
DEVI u32 cvtpk(float lo, float hi) {
  u32 r;
  asm("v_cvt_pk_bf16_f32 %0, %1, %2" : "=v"(r) : "v"(lo), "v"(hi));
  return r;
}

DEVI f32x4 mfma_bf16(s16x8 a, s16x8 b, f32x4 c) {
  return __builtin_amdgcn_mfma_f32_16x16x32_bf16(
      __builtin_bit_cast(bf16x8, a), __builtin_bit_cast(bf16x8, b), c, 0, 0, 0);
}

DEVI f32x16 mfma32(s16x8 a, s16x8 b, f32x16 c) {
  return __builtin_amdgcn_mfma_f32_32x32x16_bf16(
      __builtin_bit_cast(bf16x8, a), __builtin_bit_cast(bf16x8, b), c, 0, 0, 0);
}

DEVI void gload_lds16(const void* g, void* l) {
  __builtin_amdgcn_global_load_lds(
      (const __attribute__((address_space(1))) void*)g,
      (__attribute__((address_space(3))) void*)l, 16, 0, 0);
}

// ---------------------------------------------------------------------------
// Kernel 0: blocks < 8192: mask -> EXPANDED multiplier words.
//   MX[((b*32+kt64)*2048+q)*32 + hi*16 + w16] (u32):
//     bits (kv0+bp, kv0+bp+1), bp = 32*(w16>>3) + 8*((w16&7)>>1) + 2*(w16&1)
//     + 4*hi, encoded as 0xFFFF per KEPT half (mask==0), ready for packed AND.
//           blocks >= 8192 (192): cast W{q,k,v} fp32 -> bf16 into Wbf.
// ---------------------------------------------------------------------------
__global__ __launch_bounds__(256)
void mask_pack(const int* __restrict__ mask, u32* __restrict__ MX,
               const float* __restrict__ wq, const float* __restrict__ wk,
               const float* __restrict__ wv, u16* __restrict__ Wbf) {
  const int t = threadIdx.x, lane = t & 63;
  if (blockIdx.x >= 8192) {             // ---- W cast: 192 blocks x 4096 elems
    const u32 blk = blockIdx.x - 8192;
    const u32 g0 = blk * 4096 + (u32)t * 16;
    const u32 mtx = g0 >> 18;           // 64 blocks per matrix
    const float* src = (mtx == 0) ? wq : (mtx == 1 ? wk : wv);
    const u32 idx = g0 & 262143u;
    #pragma unroll
    for (int i = 0; i < 2; ++i) {
      f32x4 v0 = *(const f32x4*)(src + idx + i * 8);
      f32x4 v1 = *(const f32x4*)(src + idx + i * 8 + 4);
      u32x4 pk;
      pk[0] = cvtpk(v0[0], v0[1]); pk[1] = cvtpk(v0[2], v0[3]);
      pk[2] = cvtpk(v1[0], v1[1]); pk[3] = cvtpk(v1[2], v1[3]);
      *(u32x4*)(Wbf + (size_t)mtx * 262144 + idx + i * 8) = pk;
    }
    return;
  }
  const u32 gw = blockIdx.x * 4 + (t >> 6);
  const u32 W0 = gw * 16;
  // expansion params for this lane (lanes 0..31 write)
  const int hi2 = (lane >> 4) & 1, w16 = lane & 15;
  const int bp = 32 * (w16 >> 3) + 8 * ((w16 & 7) >> 1) + 2 * (w16 & 1) + 4 * hi2;
  #define MSRC(W) ((((size_t)((W) >> 16) * 2048 + ((W) & 2047u)) * 2048) \
                   + (((W) >> 11) & 31u) * 64 + lane)
  int c0 = mask[MSRC(W0)];
  int c1 = mask[MSRC(W0 + 1)];
  #pragma unroll 4
  for (u32 k = 0; k < 16; ++k) {
    u64 bits = __ballot(c0 == 0);       // keep bits, visible to all lanes
    if (lane < 32) {
      u32 m0 = (u32)(bits >> bp) & 1u;
      u32 m1 = (u32)(bits >> (bp + 1)) & 1u;
      u32 wd = (m0 ? 0xFFFFu : 0u) | (m1 ? 0xFFFF0000u : 0u);
      MX[(size_t)(W0 + k) * 32 + lane] = wd;
    }
    c0 = c1;
    if (k + 2 < 16) c1 = mask[MSRC(W0 + k + 2)];
  }
  #undef MSRC
}

// ---------------------------------------------------------------------------
// Kernel 1: QKV projections, ASYNC-PIPELINED staging (R11 form, frozen).
// ---------------------------------------------------------------------------
__global__ __launch_bounds__(256, 2)
void qkv_proj(const float* __restrict__ xq, const float* __restrict__ xkv,
              const u16* __restrict__ Wbf,
              const float* __restrict__ bq, const float* __restrict__ bk,
              const float* __restrict__ bv,
              u16* __restrict__ Qo, u16* __restrict__ Ko, u16* __restrict__ VTo)
{
  __shared__ __align__(16) char smem[57344];
  char* a32 = smem;                     // 2 x 16384: fp32 A tiles
  char* bbf = smem + 32768;             // 2 x 8192:  bf16 B tiles
  char* abf = smem + 49152;             // 8192:      bf16 A tile

  const int t = threadIdx.x, lane = t & 63, w = t >> 6;
  const int z = blockIdx.z;
  const float* X  = (z == 0) ? xq : xkv;
  const u16*   W  = Wbf + (size_t)z * 262144;
  const float* Bv = (z == 0) ? bq : (z == 1 ? bk : bv);

  const int m0 = blockIdx.x * 128, n0 = blockIdx.y * 128;
  const int wr = w >> 1, wc = w & 1, g = lane >> 4, q15 = lane & 15;
  const int srow = t >> 1, shalf = t & 1;

  f32x4 acc[4][4];
  #pragma unroll
  for (int i = 0; i < 4; ++i)
    #pragma unroll
    for (int j = 0; j < 4; ++j) acc[i][j] = (f32x4){0.f, 0.f, 0.f, 0.f};

  const float* aSrc[4];
  int aDst[4];
  #pragma unroll
  for (int i = 0; i < 4; ++i) {
    int c = w * 256 + i * 64 + lane;
    int r = c >> 3, s = c & 7, j = s ^ (r & 7);
    aSrc[i] = X + (size_t)(m0 + r) * 512 + j * 4;
    aDst[i] = (w * 256 + i * 64) * 16;
  }
  const u16* bSrc[2];
  int bDst[2];
  #pragma unroll
  for (int i = 0; i < 2; ++i) {
    int c = i * 256 + w * 64 + lane;
    int r = c >> 2, s = c & 3, j = s ^ (r & 3);
    bSrc[i] = W + (size_t)(n0 + r) * 512 + j * 8;
    bDst[i] = (i * 256 + w * 64) * 16;
  }

  #pragma unroll
  for (int i = 0; i < 4; ++i) gload_lds16(aSrc[i], a32 + aDst[i]);
  #pragma unroll
  for (int i = 0; i < 2; ++i) gload_lds16(bSrc[i], bbf + bDst[i]);
  asm volatile("" ::: "memory");

  const int wbyte = srow * 64;
  const int sw = (srow & 3) << 4;

  #pragma unroll 1
  for (int kt = 0; kt < 16; ++kt) {
    const int cur = kt & 1;
    if (kt + 1 < 16) {
      #pragma unroll
      for (int i = 0; i < 4; ++i) {
        aSrc[i] += 32;
        gload_lds16(aSrc[i], a32 + (cur ^ 1) * 16384 + aDst[i]);
      }
      #pragma unroll
      for (int i = 0; i < 2; ++i) {
        bSrc[i] += 32;
        gload_lds16(bSrc[i], bbf + (cur ^ 1) * 8192 + bDst[i]);
      }
      asm volatile("" ::: "memory");
      asm volatile("s_waitcnt vmcnt(6)" ::: "memory");
    } else {
      asm volatile("s_waitcnt vmcnt(0)" ::: "memory");
    }
    asm volatile("s_waitcnt lgkmcnt(0)" ::: "memory");
    __builtin_amdgcn_sched_barrier(0);
    asm volatile("s_barrier" ::: "memory");

    {
      const char* base = a32 + cur * 16384 + srow * 128;
      f32x4 av[4];
      #pragma unroll
      for (int jj = 0; jj < 4; ++jj) {
        int slot = (shalf * 4 + jj) ^ (srow & 7);
        av[jj] = *(const f32x4*)(base + slot * 16);
      }
      const float* pf = (const float*)av;
      #pragma unroll
      for (int half = 0; half < 2; ++half) {
        u32x4 wa;
        #pragma unroll
        for (int e2 = 0; e2 < 4; ++e2)
          wa[e2] = cvtpk(pf[half * 8 + 2 * e2], pf[half * 8 + 2 * e2 + 1]);
        *(u32x4*)(abf + wbyte + ((shalf * 32 + half * 16) ^ sw)) = wa;
      }
    }
    asm volatile("s_waitcnt lgkmcnt(0)" ::: "memory");
    __builtin_amdgcn_sched_barrier(0);
    asm volatile("s_barrier" ::: "memory");

    s16x8 afr[4], bfr[4];
    #pragma unroll
    for (int mi = 0; mi < 4; ++mi) {
      int row = wr * 64 + mi * 16 + q15;
      afr[mi] = *(const s16x8*)(abf + row * 64 + ((g * 16) ^ ((row & 3) << 4)));
    }
    #pragma unroll
    for (int ni = 0; ni < 4; ++ni) {
      int row = wc * 64 + ni * 16 + q15;
      bfr[ni] = *(const s16x8*)(bbf + cur * 8192 + row * 64 + ((g * 16) ^ ((row & 3) << 4)));
    }
    #pragma unroll
    for (int mi = 0; mi < 4; ++mi)
      #pragma unroll
      for (int ni = 0; ni < 4; ++ni)
        acc[mi][ni] = mfma_bf16(afr[mi], bfr[ni], acc[mi][ni]);
  }

  float bias[4];
  #pragma unroll
  for (int ni = 0; ni < 4; ++ni) bias[ni] = Bv[n0 + wc * 64 + ni * 16 + q15];

  if (z < 2) {
    u16* Out = z ? Ko : Qo;
    const float scale = z ? 1.0f : 0.18033688011112042f;  // 1/8 * log2(e)
    #pragma unroll
    for (int mi = 0; mi < 4; ++mi)
      #pragma unroll
      for (int ni = 0; ni < 4; ++ni)
        #pragma unroll
        for (int r = 0; r < 4; r += 2) {
          int m = m0 + wr * 64 + mi * 16 + g * 4 + r;
          int n = n0 + wc * 64 + ni * 16 + q15;
          u32 pk = cvtpk((acc[mi][ni][r] + bias[ni]) * scale,
                         (acc[mi][ni][r + 1] + bias[ni]) * scale);
          Out[(size_t)m * 512 + n]       = (u16)pk;
          Out[(size_t)(m + 1) * 512 + n] = (u16)(pk >> 16);
        }
  } else {
    __syncthreads();
    #pragma unroll
    for (int mi = 0; mi < 4; ++mi)
      #pragma unroll
      for (int ni = 0; ni < 4; ++ni)
        #pragma unroll
        for (int r = 0; r < 4; r += 2) {
          int ml = wr * 64 + mi * 16 + g * 4 + r;
          int nl = wc * 64 + ni * 16 + q15;
          *(u32*)(smem + nl * 272 + ml * 2) =
              cvtpk(acc[mi][ni][r] + bias[ni], acc[mi][ni][r + 1] + bias[ni]);
        }
    __syncthreads();
    const int b  = m0 >> 11;
    const int s0 = m0 & 2047;
    #pragma unroll
    for (int nn = 0; nn < 2; ++nn) {
      int n  = nn * 64 + (t >> 2);
      int q4 = t & 3;
      u16* dst = VTo + (size_t)(b * 512 + n0 + n) * 2048 + s0 + q4 * 32;
      #pragma unroll
      for (int jj = 0; jj < 4; ++jj)
        *(s16x8*)(dst + jj * 8) = *(const s16x8*)(smem + n * 272 + q4 * 64 + jj * 16);
    }
  }
}

// ---------------------------------------------------------------------------
// Kernel 2: fused flash attention, KVBLK=128, PRE-EXPANDED mask words:
// exp2+cvtpk run unmasked (|S|<=~30, finite), then 16 packed ANDs per half
// replace the ~190-op bit-test chain.  Mask words loaded 4x dwordx4 per half,
// issued before stage(kt+1) so counted vmcnt completes them oldest-first.
// grid.x = h + 8*b + 64*qt; block 256 = 4 waves x 32 q-rows.
// ---------------------------------------------------------------------------
__global__ __launch_bounds__(256, 2)
void attn_fwd(const u16* __restrict__ Q, const u16* __restrict__ K,
              const u16* __restrict__ VT, const u32* __restrict__ MX,
              float* __restrict__ out)
{
  __shared__ __align__(16) char lds_k[2][16384];    // [kv 128][d 64] bf16
  __shared__ __align__(16) char lds_v[2][2][8192];  // [buf][kvhalf][d64][kv64]

  const int bid = blockIdx.x;
  const int hh = bid & 7, b = (bid >> 3) & 7, qt = bid >> 6;
  const int t = threadIdx.x, lane = t & 63, w = t >> 6;
  const int l31 = lane & 31, hi = lane >> 5;
  const int qbase = qt * 128 + w * 32;
  const int swz = (l31 & 7) << 4;

  s16x8 qf[4];
  #pragma unroll
  for (int j = 0; j < 4; ++j)
    qf[j] = *(const s16x8*)(Q + (size_t)(b * 2048 + qbase + l31) * 512
                              + hh * 64 + j * 16 + hi * 8);
  asm volatile("" ::: "memory");

  f32x16 o0 = {0.f,0.f,0.f,0.f,0.f,0.f,0.f,0.f,0.f,0.f,0.f,0.f,0.f,0.f,0.f,0.f};
  f32x16 o1 = o0, o2 = o0;
  const f32x16 ZZ = o0;
  const s16x8 onesf = {0x3F80,0x3F80,0x3F80,0x3F80,0x3F80,0x3F80,0x3F80,0x3F80};

  const int srow8 = lane >> 3, slot = lane & 7;

  const u16* kP[4];
  int kD[4];
  #pragma unroll
  for (int i = 0; i < 4; ++i) {
    int rl = w * 32 + i * 8 + srow8;
    kP[i] = K + (size_t)(b * 2048 + rl) * 512 + hh * 64 + (slot ^ (rl & 7)) * 8;
    kD[i] = (w * 32 + i * 8) * 128;
  }
  const u16* vP[2];
  int vD[2];
  #pragma unroll
  for (int i = 0; i < 2; ++i) {
    int d = w * 16 + i * 8 + srow8;
    vP[i] = VT + (size_t)(b * 512 + hh * 64 + d) * 2048 + (slot ^ (d & 7)) * 8;
    vD[i] = (w * 16 + i * 8) * 128;
  }
  // mask-word base: MX[((b*32 + kt64)*2048 + q)*32 + hi*16]; kt64 step 65536
  const u32* mxP = MX + ((size_t)(b * 32) * 2048 + qbase + l31) * 32 + hi * 16;

  // prologue: stage tile 0 (kv 0..127) into buf 0
  #pragma unroll
  for (int i = 0; i < 4; ++i) gload_lds16(kP[i], &lds_k[0][kD[i]]);
  #pragma unroll
  for (int hf = 0; hf < 2; ++hf)
    #pragma unroll
    for (int i = 0; i < 2; ++i)
      gload_lds16(vP[i] + hf * 64, &lds_v[0][hf][vD[i]]);
  asm volatile("" ::: "memory");

  // one 64-kv half: QK (8 mfma) -> exp2/cvtpk -> wait -> AND -> PV+ones
#define HALF(KB, VB, MW, WAITASM) do {                                         \
    f32x16 p0 = ZZ, p1 = ZZ;                                                   \
    _Pragma("unroll")                                                          \
    for (int j = 0; j < 4; ++j) {                                              \
      s16x8 a0 = *(const s16x8*)((KB) + l31 * 128        + ((j * 32 + hi * 16) ^ swz)); \
      s16x8 a1 = *(const s16x8*)((KB) + (l31 + 32) * 128 + ((j * 32 + hi * 16) ^ swz)); \
      p0 = mfma32(a0, qf[j], p0);                                              \
      p1 = mfma32(a1, qf[j], p1);                                              \
    }                                                                          \
    u32 wds[16];                                                               \
    _Pragma("unroll")                                                          \
    for (int t2 = 0; t2 < 2; ++t2) {                                           \
      _Pragma("unroll")                                                        \
      for (int q2 = 0; q2 < 8; ++q2) {                                         \
        float s0v = t2 ? p1[2 * q2] : p0[2 * q2];                              \
        float s1v = t2 ? p1[2 * q2 + 1] : p0[2 * q2 + 1];                      \
        wds[t2 * 8 + q2] = cvtpk(EXP2(s0v), EXP2(s1v));                        \
      }                                                                        \
    }                                                                          \
    asm volatile("s_waitcnt " WAITASM ::: "memory");                           \
    _Pragma("unroll")                                                          \
    for (int w16 = 0; w16 < 16; ++w16) wds[w16] &= (MW)[w16 >> 2][w16 & 3];    \
    _Pragma("unroll")                                                          \
    for (int j = 0; j < 4; ++j) {                                              \
      const int ia = 2 * j, ib = 2 * j + 1;                                    \
      u32 wa0 = wds[(ia >> 2) * 8 + 2 * (ia & 3)];                             \
      u32 wa1 = wds[(ia >> 2) * 8 + 2 * (ia & 3) + 1];                         \
      u32 wb0 = wds[(ib >> 2) * 8 + 2 * (ib & 3)];                             \
      u32 wb1 = wds[(ib >> 2) * 8 + 2 * (ib & 3) + 1];                         \
      asm("v_permlane32_swap_b32 %0, %1" : "+v"(wa0), "+v"(wb0));              \
      asm("v_permlane32_swap_b32 %0, %1" : "+v"(wa1), "+v"(wb1));              \
      u32x4 aw = {wa0, wa1, wb0, wb1};                                         \
      s16x8 af = __builtin_bit_cast(s16x8, aw);                                \
      s16x8 v0 = *(const s16x8*)((VB) + l31 * 128        + ((j * 32 + hi * 16) ^ swz)); \
      s16x8 v1 = *(const s16x8*)((VB) + (l31 + 32) * 128 + ((j * 32 + hi * 16) ^ swz)); \
      o0 = mfma32(af, v0, o0);                                                 \
      o1 = mfma32(af, v1, o1);                                                 \
      o2 = mfma32(af, onesf, o2);                                              \
    }                                                                          \
  } while (0)

  #pragma unroll 1
  for (int kt = 0; kt < 16; ++kt) {
    const int cur = kt & 1;
    // a: mask words for tile kt (oldest in queue after this iter's issues)
    u32x4 mwA[4], mwB[4];
    #pragma unroll
    for (int i = 0; i < 4; ++i) mwA[i] = *(const u32x4*)(mxP + i * 4);
    #pragma unroll
    for (int i = 0; i < 4; ++i) mwB[i] = *(const u32x4*)(mxP + 65536 + i * 4);
    asm volatile("" ::: "memory");
    if (kt + 1 < 16) {
      // b: stage(kt+1)
      #pragma unroll
      for (int i = 0; i < 4; ++i) kP[i] += 65536;
      #pragma unroll
      for (int i = 0; i < 2; ++i) vP[i] += 128;
      mxP += 131072;
      #pragma unroll
      for (int i = 0; i < 4; ++i) gload_lds16(kP[i], &lds_k[cur ^ 1][kD[i]]);
      #pragma unroll
      for (int hf = 0; hf < 2; ++hf)
        #pragma unroll
        for (int i = 0; i < 2; ++i)
          gload_lds16(vP[i] + hf * 64, &lds_v[cur ^ 1][hf][vD[i]]);
      asm volatile("" ::: "memory");
      // outstanding: stage(kt)=8 (oldest), mask(kt)=8, stage(kt+1)=8
      asm volatile("s_waitcnt vmcnt(16)" ::: "memory");  // stage(kt) done
    } else {
      asm volatile("s_waitcnt vmcnt(8)" ::: "memory");   // stage(15) done
    }
    asm volatile("s_barrier" ::: "memory");

    if (kt + 1 < 16) {
      HALF(&lds_k[cur][0],    &lds_v[cur][0][0], mwA, "vmcnt(12)");
      HALF(&lds_k[cur][8192], &lds_v[cur][1][0], mwB, "vmcnt(8)");
    } else {
      HALF(&lds_k[cur][0],    &lds_v[cur][0][0], mwA, "vmcnt(4)");
      HALF(&lds_k[cur][8192], &lds_v[cur][1][0], mwB, "vmcnt(0)");
    }

    asm volatile("s_waitcnt lgkmcnt(0)" ::: "memory");
    __builtin_amdgcn_sched_barrier(0);
    asm volatile("s_barrier" ::: "memory");
  }
#undef HALF

  // ---- epilogue: o2[reg] IS the row denominator for o0/o1[reg] ----
  #pragma unroll
  for (int reg = 0; reg < 16; ++reg) {
    const int ql = (reg & 3) + 8 * (reg >> 2) + 4 * hi;
    const float linv = 1.0f / o2[reg];
    float* po = out + (size_t)(b * 2048 + qbase + ql) * 512 + hh * 64 + l31;
    po[0]  = o0[reg] * linv;
    po[32] = o1[reg] * linv;
  }
}

extern "C" void kernel_launch(void* const* d_in, const int* in_sizes, int n_in,
                              void* d_out, int out_size, void* d_ws, size_t ws_size,
                              hipStream_t stream) {
  const float* xq  = (const float*)d_in[0];
  const float* xkv = (const float*)d_in[1];
  const int*   msk = (const int*)d_in[2];
  const float* wq  = (const float*)d_in[3];
  const float* bq  = (const float*)d_in[4];
  const float* wk  = (const float*)d_in[5];
  const float* bk  = (const float*)d_in[6];
  const float* wv  = (const float*)d_in[7];
  const float* bv  = (const float*)d_in[8];

  u16* Qw  = (u16*)d_ws;                         // [16384][512] bf16 (x 0.1803)
  u16* Kw  = Qw + (size_t)16384 * 512;           // [16384][512] bf16
  u16* VT  = Kw + (size_t)16384 * 512;           // [4096][2048] bf16 (V^T)
  u32* MX  = (u32*)(VT + (size_t)4096 * 2048);   // [8*32][2048][2][16] mask words
  u16* Wbf = (u16*)(MX + (size_t)8 * 32 * 2048 * 32);  // [3][512][512] bf16 W

  mask_pack<<<dim3(8384), 256, 0, stream>>>(msk, MX, wq, wk, wv, Wbf);
  qkv_proj<<<dim3(128, 4, 3), 256, 0, stream>>>(xq, xkv, Wbf, bq, bk, bv,
                                                Qw, Kw, VT);
  attn_fwd<<<dim3(1024), 256, 0, stream>>>(Qw, Kw, VT, MX, (float*)d_out);
}

// Round 14
// 215.577 us; speedup vs baseline: 1.0419x; 1.0419x over previous
//
#include <hip/hip_runtime.h>
#include <hip/hip_bf16.h>
#include <math.h>

typedef float  f32x4  __attribute__((ext_vector_type(4)));
typedef float  f32x16 __attribute__((ext_vector_type(16)));
typedef short  s16x8  __attribute__((ext_vector_type(8)));
typedef __bf16 bf16x8 __attribute__((ext_vector_type(8)));
typedef unsigned int u32;
typedef unsigned int u32x4 __attribute__((ext_vector_type(4)));
typedef unsigned short u16;
typedef unsigned long long u64;

#define DEVI static __device__ __forceinline__

#if defined(__has_builtin) && __has_builtin(__builtin_amdgcn_exp2f)
#define EXP2(x) __builtin_amdgcn_exp2f(x)
#else
#define EXP2(x) exp2f(x)
#endif

// one-instruction packed f32->bf16 RNE pair (v_cvt_pk_bf16_f32)
DEVI u32 cvtpk(float lo, float hi) {
  u32 r;
  asm("v_cvt_pk_bf16_f32 %0, %1, %2" : "=v"(r) : "v"(lo), "v"(hi));
  return r;
}

DEVI f32x4 mfma_bf16(s16x8 a, s16x8 b, f32x4 c) {
  return __builtin_amdgcn_mfma_f32_16x16x32_bf16(
      __builtin_bit_cast(bf16x8, a), __builtin_bit_cast(bf16x8, b), c, 0, 0, 0);
}

DEVI f32x16 mfma32(s16x8 a, s16x8 b, f32x16 c) {
  return __builtin_amdgcn_mfma_f32_32x32x16_bf16(
      __builtin_bit_cast(bf16x8, a), __builtin_bit_cast(bf16x8, b), c, 0, 0, 0);
}

DEVI void gload_lds16(const void* g, void* l) {
  __builtin_amdgcn_global_load_lds(
      (const __attribute__((address_space(1))) void*)g,
      (__attribute__((address_space(3))) void*)l, 16, 0, 0);
}

// ---------------------------------------------------------------------------
// Kernel 0: blocks < 8192: mask -> EXPANDED multiplier words.
//   MX[((b*32+kt64)*2048+q)*32 + hi*16 + w16] (u32):
//     bits (kv0+bp, kv0+bp+1), bp = 32*(w16>>3) + 8*((w16&7)>>1) + 2*(w16&1)
//     + 4*hi, encoded as 0xFFFF per KEPT half (mask==0), ready for packed AND.
//           blocks >= 8192 (192): cast W{q,k,v} fp32 -> bf16 into Wbf.
// ---------------------------------------------------------------------------
__global__ __launch_bounds__(256)
void mask_pack(const int* __restrict__ mask, u32* __restrict__ MX,
               const float* __restrict__ wq, const float* __restrict__ wk,
               const float* __restrict__ wv, u16* __restrict__ Wbf) {
  const int t = threadIdx.x, lane = t & 63;
  if (blockIdx.x >= 8192) {             // ---- W cast: 192 blocks x 4096 elems
    const u32 blk = blockIdx.x - 8192;
    const u32 g0 = blk * 4096 + (u32)t * 16;
    const u32 mtx = g0 >> 18;           // 64 blocks per matrix
    const float* src = (mtx == 0) ? wq : (mtx == 1 ? wk : wv);
    const u32 idx = g0 & 262143u;
    #pragma unroll
    for (int i = 0; i < 2; ++i) {
      f32x4 v0 = *(const f32x4*)(src + idx + i * 8);
      f32x4 v1 = *(const f32x4*)(src + idx + i * 8 + 4);
      u32x4 pk;
      pk[0] = cvtpk(v0[0], v0[1]); pk[1] = cvtpk(v0[2], v0[3]);
      pk[2] = cvtpk(v1[0], v1[1]); pk[3] = cvtpk(v1[2], v1[3]);
      *(u32x4*)(Wbf + (size_t)mtx * 262144 + idx + i * 8) = pk;
    }
    return;
  }
  const u32 gw = blockIdx.x * 4 + (t >> 6);
  const u32 W0 = gw * 16;
  // expansion params for this lane (lanes 0..31 write)
  const int hi2 = (lane >> 4) & 1, w16 = lane & 15;
  const int bp = 32 * (w16 >> 3) + 8 * ((w16 & 7) >> 1) + 2 * (w16 & 1) + 4 * hi2;
  #define MSRC(W) ((((size_t)((W) >> 16) * 2048 + ((W) & 2047u)) * 2048) \
                   + (((W) >> 11) & 31u) * 64 + lane)
  int c0 = mask[MSRC(W0)];
  int c1 = mask[MSRC(W0 + 1)];
  #pragma unroll 4
  for (u32 k = 0; k < 16; ++k) {
    u64 bits = __ballot(c0 == 0);       // keep bits, visible to all lanes
    if (lane < 32) {
      u32 m0 = (u32)(bits >> bp) & 1u;
      u32 m1 = (u32)(bits >> (bp + 1)) & 1u;
      u32 wd = (m0 ? 0xFFFFu : 0u) | (m1 ? 0xFFFF0000u : 0u);
      MX[(size_t)(W0 + k) * 32 + lane] = wd;
    }
    c0 = c1;
    if (k + 2 < 16) c1 = mask[MSRC(W0 + k + 2)];
  }
  #undef MSRC
}

// ---------------------------------------------------------------------------
// Kernel 1: QKV projections, ASYNC-PIPELINED staging (R11 form, frozen).
// ---------------------------------------------------------------------------
__global__ __launch_bounds__(256, 2)
void qkv_proj(const float* __restrict__ xq, const float* __restrict__ xkv,
              const u16* __restrict__ Wbf,
              const float* __restrict__ bq, const float* __restrict__ bk,
              const float* __restrict__ bv,
              u16* __restrict__ Qo, u16* __restrict__ Ko, u16* __restrict__ VTo)
{
  __shared__ __align__(16) char smem[57344];
  char* a32 = smem;                     // 2 x 16384: fp32 A tiles
  char* bbf = smem + 32768;             // 2 x 8192:  bf16 B tiles
  char* abf = smem + 49152;             // 8192:      bf16 A tile

  const int t = threadIdx.x, lane = t & 63, w = t >> 6;
  const int z = blockIdx.z;
  const float* X  = (z == 0) ? xq : xkv;
  const u16*   W  = Wbf + (size_t)z * 262144;
  const float* Bv = (z == 0) ? bq : (z == 1 ? bk : bv);

  const int m0 = blockIdx.x * 128, n0 = blockIdx.y * 128;
  const int wr = w >> 1, wc = w & 1, g = lane >> 4, q15 = lane & 15;
  const int srow = t >> 1, shalf = t & 1;

  f32x4 acc[4][4];
  #pragma unroll
  for (int i = 0; i < 4; ++i)
    #pragma unroll
    for (int j = 0; j < 4; ++j) acc[i][j] = (f32x4){0.f, 0.f, 0.f, 0.f};

  const float* aSrc[4];
  int aDst[4];
  #pragma unroll
  for (int i = 0; i < 4; ++i) {
    int c = w * 256 + i * 64 + lane;
    int r = c >> 3, s = c & 7, j = s ^ (r & 7);
    aSrc[i] = X + (size_t)(m0 + r) * 512 + j * 4;
    aDst[i] = (w * 256 + i * 64) * 16;
  }
  const u16* bSrc[2];
  int bDst[2];
  #pragma unroll
  for (int i = 0; i < 2; ++i) {
    int c = i * 256 + w * 64 + lane;
    int r = c >> 2, s = c & 3, j = s ^ (r & 3);
    bSrc[i] = W + (size_t)(n0 + r) * 512 + j * 8;
    bDst[i] = (i * 256 + w * 64) * 16;
  }

  #pragma unroll
  for (int i = 0; i < 4; ++i) gload_lds16(aSrc[i], a32 + aDst[i]);
  #pragma unroll
  for (int i = 0; i < 2; ++i) gload_lds16(bSrc[i], bbf + bDst[i]);
  asm volatile("" ::: "memory");

  const int wbyte = srow * 64;
  const int sw = (srow & 3) << 4;

  #pragma unroll 1
  for (int kt = 0; kt < 16; ++kt) {
    const int cur = kt & 1;
    if (kt + 1 < 16) {
      #pragma unroll
      for (int i = 0; i < 4; ++i) {
        aSrc[i] += 32;
        gload_lds16(aSrc[i], a32 + (cur ^ 1) * 16384 + aDst[i]);
      }
      #pragma unroll
      for (int i = 0; i < 2; ++i) {
        bSrc[i] += 32;
        gload_lds16(bSrc[i], bbf + (cur ^ 1) * 8192 + bDst[i]);
      }
      asm volatile("" ::: "memory");
      asm volatile("s_waitcnt vmcnt(6)" ::: "memory");
    } else {
      asm volatile("s_waitcnt vmcnt(0)" ::: "memory");
    }
    asm volatile("s_waitcnt lgkmcnt(0)" ::: "memory");
    __builtin_amdgcn_sched_barrier(0);
    asm volatile("s_barrier" ::: "memory");

    {
      const char* base = a32 + cur * 16384 + srow * 128;
      f32x4 av[4];
      #pragma unroll
      for (int jj = 0; jj < 4; ++jj) {
        int slot = (shalf * 4 + jj) ^ (srow & 7);
        av[jj] = *(const f32x4*)(base + slot * 16);
      }
      const float* pf = (const float*)av;
      #pragma unroll
      for (int half = 0; half < 2; ++half) {
        u32x4 wa;
        #pragma unroll
        for (int e2 = 0; e2 < 4; ++e2)
          wa[e2] = cvtpk(pf[half * 8 + 2 * e2], pf[half * 8 + 2 * e2 + 1]);
        *(u32x4*)(abf + wbyte + ((shalf * 32 + half * 16) ^ sw)) = wa;
      }
    }
    asm volatile("s_waitcnt lgkmcnt(0)" ::: "memory");
    __builtin_amdgcn_sched_barrier(0);
    asm volatile("s_barrier" ::: "memory");

    s16x8 afr[4], bfr[4];
    #pragma unroll
    for (int mi = 0; mi < 4; ++mi) {
      int row = wr * 64 + mi * 16 + q15;
      afr[mi] = *(const s16x8*)(abf + row * 64 + ((g * 16) ^ ((row & 3) << 4)));
    }
    #pragma unroll
    for (int ni = 0; ni < 4; ++ni) {
      int row = wc * 64 + ni * 16 + q15;
      bfr[ni] = *(const s16x8*)(bbf + cur * 8192 + row * 64 + ((g * 16) ^ ((row & 3) << 4)));
    }
    #pragma unroll
    for (int mi = 0; mi < 4; ++mi)
      #pragma unroll
      for (int ni = 0; ni < 4; ++ni)
        acc[mi][ni] = mfma_bf16(afr[mi], bfr[ni], acc[mi][ni]);
  }

  float bias[4];
  #pragma unroll
  for (int ni = 0; ni < 4; ++ni) bias[ni] = Bv[n0 + wc * 64 + ni * 16 + q15];

  if (z < 2) {
    u16* Out = z ? Ko : Qo;
    const float scale = z ? 1.0f : 0.18033688011112042f;  // 1/8 * log2(e)
    #pragma unroll
    for (int mi = 0; mi < 4; ++mi)
      #pragma unroll
      for (int ni = 0; ni < 4; ++ni)
        #pragma unroll
        for (int r = 0; r < 4; r += 2) {
          int m = m0 + wr * 64 + mi * 16 + g * 4 + r;
          int n = n0 + wc * 64 + ni * 16 + q15;
          u32 pk = cvtpk((acc[mi][ni][r] + bias[ni]) * scale,
                         (acc[mi][ni][r + 1] + bias[ni]) * scale);
          Out[(size_t)m * 512 + n]       = (u16)pk;
          Out[(size_t)(m + 1) * 512 + n] = (u16)(pk >> 16);
        }
  } else {
    __syncthreads();
    #pragma unroll
    for (int mi = 0; mi < 4; ++mi)
      #pragma unroll
      for (int ni = 0; ni < 4; ++ni)
        #pragma unroll
        for (int r = 0; r < 4; r += 2) {
          int ml = wr * 64 + mi * 16 + g * 4 + r;
          int nl = wc * 64 + ni * 16 + q15;
          *(u32*)(smem + nl * 272 + ml * 2) =
              cvtpk(acc[mi][ni][r] + bias[ni], acc[mi][ni][r + 1] + bias[ni]);
        }
    __syncthreads();
    const int b  = m0 >> 11;
    const int s0 = m0 & 2047;
    #pragma unroll
    for (int nn = 0; nn < 2; ++nn) {
      int n  = nn * 64 + (t >> 2);
      int q4 = t & 3;
      u16* dst = VTo + (size_t)(b * 512 + n0 + n) * 2048 + s0 + q4 * 32;
      #pragma unroll
      for (int jj = 0; jj < 4; ++jj)
        *(s16x8*)(dst + jj * 8) = *(const s16x8*)(smem + n * 272 + q4 * 64 + jj * 16);
    }
  }
}

// ---------------------------------------------------------------------------
// Kernel 2: fused flash attention, KVBLK=128, pre-expanded mask words.
// GRID DECODE SWAPPED (b fastest): with round-robin blockIdx->XCD dispatch,
// XCD = bid%8 = b, so ALL blocks of batch b (every h, qt) co-locate on one
// XCD -> MX slices shared by 8 h-blocks and K/VT shared by 16 qt-blocks hit
// that XCD's private L2 instead of re-fetching from HBM (R13: 318 MB FETCH).
// grid.x = b + 8*h + 64*qt; block 256 = 4 waves x 32 q-rows.
// ---------------------------------------------------------------------------
__global__ __launch_bounds__(256, 2)
void attn_fwd(const u16* __restrict__ Q, const u16* __restrict__ K,
              const u16* __restrict__ VT, const u32* __restrict__ MX,
              float* __restrict__ out)
{
  __shared__ __align__(16) char lds_k[2][16384];    // [kv 128][d 64] bf16
  __shared__ __align__(16) char lds_v[2][2][8192];  // [buf][kvhalf][d64][kv64]

  const int bid = blockIdx.x;
  const int b = bid & 7, hh = (bid >> 3) & 7, qt = bid >> 6;   // b fastest!
  const int t = threadIdx.x, lane = t & 63, w = t >> 6;
  const int l31 = lane & 31, hi = lane >> 5;
  const int qbase = qt * 128 + w * 32;
  const int swz = (l31 & 7) << 4;

  s16x8 qf[4];
  #pragma unroll
  for (int j = 0; j < 4; ++j)
    qf[j] = *(const s16x8*)(Q + (size_t)(b * 2048 + qbase + l31) * 512
                              + hh * 64 + j * 16 + hi * 8);
  asm volatile("" ::: "memory");

  f32x16 o0 = {0.f,0.f,0.f,0.f,0.f,0.f,0.f,0.f,0.f,0.f,0.f,0.f,0.f,0.f,0.f,0.f};
  f32x16 o1 = o0, o2 = o0;
  const f32x16 ZZ = o0;
  const s16x8 onesf = {0x3F80,0x3F80,0x3F80,0x3F80,0x3F80,0x3F80,0x3F80,0x3F80};

  const int srow8 = lane >> 3, slot = lane & 7;

  const u16* kP[4];
  int kD[4];
  #pragma unroll
  for (int i = 0; i < 4; ++i) {
    int rl = w * 32 + i * 8 + srow8;
    kP[i] = K + (size_t)(b * 2048 + rl) * 512 + hh * 64 + (slot ^ (rl & 7)) * 8;
    kD[i] = (w * 32 + i * 8) * 128;
  }
  const u16* vP[2];
  int vD[2];
  #pragma unroll
  for (int i = 0; i < 2; ++i) {
    int d = w * 16 + i * 8 + srow8;
    vP[i] = VT + (size_t)(b * 512 + hh * 64 + d) * 2048 + (slot ^ (d & 7)) * 8;
    vD[i] = (w * 16 + i * 8) * 128;
  }
  // mask-word base: MX[((b*32 + kt64)*2048 + q)*32 + hi*16]; kt64 step 65536
  const u32* mxP = MX + ((size_t)(b * 32) * 2048 + qbase + l31) * 32 + hi * 16;

  // prologue: stage tile 0 (kv 0..127) into buf 0
  #pragma unroll
  for (int i = 0; i < 4; ++i) gload_lds16(kP[i], &lds_k[0][kD[i]]);
  #pragma unroll
  for (int hf = 0; hf < 2; ++hf)
    #pragma unroll
    for (int i = 0; i < 2; ++i)
      gload_lds16(vP[i] + hf * 64, &lds_v[0][hf][vD[i]]);
  asm volatile("" ::: "memory");

  // one 64-kv half: QK (8 mfma) -> exp2/cvtpk -> wait -> AND -> PV+ones
#define HALF(KB, VB, MW, WAITASM) do {                                         \
    f32x16 p0 = ZZ, p1 = ZZ;                                                   \
    _Pragma("unroll")                                                          \
    for (int j = 0; j < 4; ++j) {                                              \
      s16x8 a0 = *(const s16x8*)((KB) + l31 * 128        + ((j * 32 + hi * 16) ^ swz)); \
      s16x8 a1 = *(const s16x8*)((KB) + (l31 + 32) * 128 + ((j * 32 + hi * 16) ^ swz)); \
      p0 = mfma32(a0, qf[j], p0);                                              \
      p1 = mfma32(a1, qf[j], p1);                                              \
    }                                                                          \
    u32 wds[16];                                                               \
    _Pragma("unroll")                                                          \
    for (int t2 = 0; t2 < 2; ++t2) {                                           \
      _Pragma("unroll")                                                        \
      for (int q2 = 0; q2 < 8; ++q2) {                                         \
        float s0v = t2 ? p1[2 * q2] : p0[2 * q2];                              \
        float s1v = t2 ? p1[2 * q2 + 1] : p0[2 * q2 + 1];                      \
        wds[t2 * 8 + q2] = cvtpk(EXP2(s0v), EXP2(s1v));                        \
      }                                                                        \
    }                                                                          \
    asm volatile("s_waitcnt " WAITASM ::: "memory");                           \
    _Pragma("unroll")                                                          \
    for (int w16 = 0; w16 < 16; ++w16) wds[w16] &= (MW)[w16 >> 2][w16 & 3];    \
    _Pragma("unroll")                                                          \
    for (int j = 0; j < 4; ++j) {                                              \
      const int ia = 2 * j, ib = 2 * j + 1;                                    \
      u32 wa0 = wds[(ia >> 2) * 8 + 2 * (ia & 3)];                             \
      u32 wa1 = wds[(ia >> 2) * 8 + 2 * (ia & 3) + 1];                         \
      u32 wb0 = wds[(ib >> 2) * 8 + 2 * (ib & 3)];                             \
      u32 wb1 = wds[(ib >> 2) * 8 + 2 * (ib & 3) + 1];                         \
      asm("v_permlane32_swap_b32 %0, %1" : "+v"(wa0), "+v"(wb0));              \
      asm("v_permlane32_swap_b32 %0, %1" : "+v"(wa1), "+v"(wb1));              \
      u32x4 aw = {wa0, wa1, wb0, wb1};                                         \
      s16x8 af = __builtin_bit_cast(s16x8, aw);                                \
      s16x8 v0 = *(const s16x8*)((VB) + l31 * 128        + ((j * 32 + hi * 16) ^ swz)); \
      s16x8 v1 = *(const s16x8*)((VB) + (l31 + 32) * 128 + ((j * 32 + hi * 16) ^ swz)); \
      o0 = mfma32(af, v0, o0);                                                 \
      o1 = mfma32(af, v1, o1);                                                 \
      o2 = mfma32(af, onesf, o2);                                              \
    }                                                                          \
  } while (0)

  #pragma unroll 1
  for (int kt = 0; kt < 16; ++kt) {
    const int cur = kt & 1;
    // a: mask words for tile kt (oldest in queue after this iter's issues)
    u32x4 mwA[4], mwB[4];
    #pragma unroll
    for (int i = 0; i < 4; ++i) mwA[i] = *(const u32x4*)(mxP + i * 4);
    #pragma unroll
    for (int i = 0; i < 4; ++i) mwB[i] = *(const u32x4*)(mxP + 65536 + i * 4);
    asm volatile("" ::: "memory");
    if (kt + 1 < 16) {
      // b: stage(kt+1)
      #pragma unroll
      for (int i = 0; i < 4; ++i) kP[i] += 65536;
      #pragma unroll
      for (int i = 0; i < 2; ++i) vP[i] += 128;
      mxP += 131072;
      #pragma unroll
      for (int i = 0; i < 4; ++i) gload_lds16(kP[i], &lds_k[cur ^ 1][kD[i]]);
      #pragma unroll
      for (int hf = 0; hf < 2; ++hf)
        #pragma unroll
        for (int i = 0; i < 2; ++i)
          gload_lds16(vP[i] + hf * 64, &lds_v[cur ^ 1][hf][vD[i]]);
      asm volatile("" ::: "memory");
      // outstanding: stage(kt)=8 (oldest), mask(kt)=8, stage(kt+1)=8
      asm volatile("s_waitcnt vmcnt(16)" ::: "memory");  // stage(kt) done
    } else {
      asm volatile("s_waitcnt vmcnt(8)" ::: "memory");   // stage(15) done
    }
    asm volatile("s_barrier" ::: "memory");

    if (kt + 1 < 16) {
      HALF(&lds_k[cur][0],    &lds_v[cur][0][0], mwA, "vmcnt(12)");
      HALF(&lds_k[cur][8192], &lds_v[cur][1][0], mwB, "vmcnt(8)");
    } else {
      HALF(&lds_k[cur][0],    &lds_v[cur][0][0], mwA, "vmcnt(4)");
      HALF(&lds_k[cur][8192], &lds_v[cur][1][0], mwB, "vmcnt(0)");
    }

    asm volatile("s_waitcnt lgkmcnt(0)" ::: "memory");
    __builtin_amdgcn_sched_barrier(0);
    asm volatile("s_barrier" ::: "memory");
  }
#undef HALF

  // ---- epilogue: o2[reg] IS the row denominator for o0/o1[reg] ----
  #pragma unroll
  for (int reg = 0; reg < 16; ++reg) {
    const int ql = (reg & 3) + 8 * (reg >> 2) + 4 * hi;
    const float linv = 1.0f / o2[reg];
    float* po = out + (size_t)(b * 2048 + qbase + ql) * 512 + hh * 64 + l31;
    po[0]  = o0[reg] * linv;
    po[32] = o1[reg] * linv;
  }
}

extern "C" void kernel_launch(void* const* d_in, const int* in_sizes, int n_in,
                              void* d_out, int out_size, void* d_ws, size_t ws_size,
                              hipStream_t stream) {
  const float* xq  = (const float*)d_in[0];
  const float* xkv = (const float*)d_in[1];
  const int*   msk = (const int*)d_in[2];
  const float* wq  = (const float*)d_in[3];
  const float* bq  = (const float*)d_in[4];
  const float* wk  = (const float*)d_in[5];
  const float* bk  = (const float*)d_in[6];
  const float* wv  = (const float*)d_in[7];
  const float* bv  = (const float*)d_in[8];

  u16* Qw  = (u16*)d_ws;                         // [16384][512] bf16 (x 0.1803)
  u16* Kw  = Qw + (size_t)16384 * 512;           // [16384][512] bf16
  u16* VT  = Kw + (size_t)16384 * 512;           // [4096][2048] bf16 (V^T)
  u32* MX  = (u32*)(VT + (size_t)4096 * 2048);   // [8*32][2048][2][16] mask words
  u16* Wbf = (u16*)(MX + (size_t)8 * 32 * 2048 * 32);  // [3][512][512] bf16 W

  mask_pack<<<dim3(8384), 256, 0, stream>>>(msk, MX, wq, wk, wv, Wbf);
  qkv_proj<<<dim3(128, 4, 3), 256, 0, stream>>>(xq, xkv, Wbf, bq, bk, bv,
                                                Qw, Kw, VT);
  attn_fwd<<<dim3(1024), 256, 0, stream>>>(Qw, Kw, VT, MX, (float*)d_out);
}

// Round 15
// 193.821 us; speedup vs baseline: 1.1588x; 1.1122x over previous
//
#include <hip/hip_runtime.h>
#include <hip/hip_bf16.h>
#include <math.h>

typedef float  f32x4  __attribute__((ext_vector_type(4)));
typedef float  f32x16 __attribute__((ext_vector_type(16)));
typedef short  s16x8  __attribute__((ext_vector_type(8)));
typedef __bf16 bf16x8 __attribute__((ext_vector_type(8)));
typedef unsigned int u32;
typedef unsigned int u32x4 __attribute__((ext_vector_type(4)));
typedef unsigned short u16;
typedef unsigned long long u64;

#define DEVI static __device__ __forceinline__

#if defined(__has_builtin) && __has_builtin(__builtin_amdgcn_exp2f)
#define EXP2(x) __builtin_amdgcn_exp2f(x)
#else
#define EXP2(x) exp2f(x)
#endif

// one-instruction packed f32->bf16 RNE pair (v_cvt_pk_bf16_f32)
DEVI u32 cvtpk(float lo, float hi) {
  u32 r;
  asm("v_cvt_pk_bf16_f32 %0, %1, %2" : "=v"(r) : "v"(lo), "v"(hi));
  return r;
}

DEVI f32x4 mfma_bf16(s16x8 a, s16x8 b, f32x4 c) {
  return __builtin_amdgcn_mfma_f32_16x16x32_bf16(
      __builtin_bit_cast(bf16x8, a), __builtin_bit_cast(bf16x8, b), c, 0, 0, 0);
}

DEVI f32x16 mfma32(s16x8 a, s16x8 b, f32x16 c) {
  return __builtin_amdgcn_mfma_f32_32x32x16_bf16(
      __builtin_bit_cast(bf16x8, a), __builtin_bit_cast(bf16x8, b), c, 0, 0, 0);
}

DEVI void gload_lds16(const void* g, void* l) {
  __builtin_amdgcn_global_load_lds(
      (const __attribute__((address_space(1))) void*)g,
      (__attribute__((address_space(3))) void*)l, 16, 0, 0);
}

// ---------------------------------------------------------------------------
// Kernel 0: blocks < 8192: bit-pack KEEP bits (16 words/wave, 2-deep ahead).
//           blocks >= 8192 (192): cast W{q,k,v} fp32 -> bf16 into Wbf.
// word (b,kt,q): bit l == 1  iff  kv = kt*64+l is KEPT (mask == 0).
// ---------------------------------------------------------------------------
__global__ __launch_bounds__(256)
void mask_pack(const int* __restrict__ mask, u64* __restrict__ mp,
               const float* __restrict__ wq, const float* __restrict__ wk,
               const float* __restrict__ wv, u16* __restrict__ Wbf) {
  const int t = threadIdx.x, lane = t & 63;
  if (blockIdx.x >= 8192) {             // ---- W cast: 192 blocks x 4096 elems
    const u32 blk = blockIdx.x - 8192;
    const u32 g0 = blk * 4096 + (u32)t * 16;
    const u32 mtx = g0 >> 18;           // 64 blocks per matrix
    const float* src = (mtx == 0) ? wq : (mtx == 1 ? wk : wv);
    const u32 idx = g0 & 262143u;
    #pragma unroll
    for (int i = 0; i < 2; ++i) {
      f32x4 v0 = *(const f32x4*)(src + idx + i * 8);
      f32x4 v1 = *(const f32x4*)(src + idx + i * 8 + 4);
      u32x4 pk;
      pk[0] = cvtpk(v0[0], v0[1]); pk[1] = cvtpk(v0[2], v0[3]);
      pk[2] = cvtpk(v1[0], v1[1]); pk[3] = cvtpk(v1[2], v1[3]);
      *(u32x4*)(Wbf + (size_t)mtx * 262144 + idx + i * 8) = pk;
    }
    return;
  }
  const u32 gw = blockIdx.x * 4 + (t >> 6);
  const u32 W0 = gw * 16;
  #define MSRC(W) ((((size_t)((W) >> 16) * 2048 + ((W) & 2047u)) * 2048) \
                   + (((W) >> 11) & 31u) * 64 + lane)
  int c0 = mask[MSRC(W0)];
  int c1 = mask[MSRC(W0 + 1)];
  #pragma unroll 4
  for (u32 k = 0; k < 16; ++k) {
    u64 bits = __ballot(c0 == 0);
    if (lane == 0) mp[W0 + k] = bits;
    c0 = c1;
    if (k + 2 < 16) c1 = mask[MSRC(W0 + k + 2)];
  }
  #undef MSRC
}

// ---------------------------------------------------------------------------
// Kernel 1: QKV projections, ASYNC-PIPELINED staging (R11 form, frozen).
// ---------------------------------------------------------------------------
__global__ __launch_bounds__(256, 2)
void qkv_proj(const float* __restrict__ xq, const float* __restrict__ xkv,
              const u16* __restrict__ Wbf,
              const float* __restrict__ bq, const float* __restrict__ bk,
              const float* __restrict__ bv,
              u16* __restrict__ Qo, u16* __restrict__ Ko, u16* __restrict__ VTo)
{
  __shared__ __align__(16) char smem[57344];
  char* a32 = smem;                     // 2 x 16384: fp32 A tiles
  char* bbf = smem + 32768;             // 2 x 8192:  bf16 B tiles
  char* abf = smem + 49152;             // 8192:      bf16 A tile

  const int t = threadIdx.x, lane = t & 63, w = t >> 6;
  const int z = blockIdx.z;
  const float* X  = (z == 0) ? xq : xkv;
  const u16*   W  = Wbf + (size_t)z * 262144;
  const float* Bv = (z == 0) ? bq : (z == 1 ? bk : bv);

  const int m0 = blockIdx.x * 128, n0 = blockIdx.y * 128;
  const int wr = w >> 1, wc = w & 1, g = lane >> 4, q15 = lane & 15;
  const int srow = t >> 1, shalf = t & 1;

  f32x4 acc[4][4];
  #pragma unroll
  for (int i = 0; i < 4; ++i)
    #pragma unroll
    for (int j = 0; j < 4; ++j) acc[i][j] = (f32x4){0.f, 0.f, 0.f, 0.f};

  const float* aSrc[4];
  int aDst[4];
  #pragma unroll
  for (int i = 0; i < 4; ++i) {
    int c = w * 256 + i * 64 + lane;
    int r = c >> 3, s = c & 7, j = s ^ (r & 7);
    aSrc[i] = X + (size_t)(m0 + r) * 512 + j * 4;
    aDst[i] = (w * 256 + i * 64) * 16;
  }
  const u16* bSrc[2];
  int bDst[2];
  #pragma unroll
  for (int i = 0; i < 2; ++i) {
    int c = i * 256 + w * 64 + lane;
    int r = c >> 2, s = c & 3, j = s ^ (r & 3);
    bSrc[i] = W + (size_t)(n0 + r) * 512 + j * 8;
    bDst[i] = (i * 256 + w * 64) * 16;
  }

  #pragma unroll
  for (int i = 0; i < 4; ++i) gload_lds16(aSrc[i], a32 + aDst[i]);
  #pragma unroll
  for (int i = 0; i < 2; ++i) gload_lds16(bSrc[i], bbf + bDst[i]);
  asm volatile("" ::: "memory");

  const int wbyte = srow * 64;
  const int sw = (srow & 3) << 4;

  #pragma unroll 1
  for (int kt = 0; kt < 16; ++kt) {
    const int cur = kt & 1;
    if (kt + 1 < 16) {
      #pragma unroll
      for (int i = 0; i < 4; ++i) {
        aSrc[i] += 32;
        gload_lds16(aSrc[i], a32 + (cur ^ 1) * 16384 + aDst[i]);
      }
      #pragma unroll
      for (int i = 0; i < 2; ++i) {
        bSrc[i] += 32;
        gload_lds16(bSrc[i], bbf + (cur ^ 1) * 8192 + bDst[i]);
      }
      asm volatile("" ::: "memory");
      asm volatile("s_waitcnt vmcnt(6)" ::: "memory");
    } else {
      asm volatile("s_waitcnt vmcnt(0)" ::: "memory");
    }
    asm volatile("s_waitcnt lgkmcnt(0)" ::: "memory");
    __builtin_amdgcn_sched_barrier(0);
    asm volatile("s_barrier" ::: "memory");

    {
      const char* base = a32 + cur * 16384 + srow * 128;
      f32x4 av[4];
      #pragma unroll
      for (int jj = 0; jj < 4; ++jj) {
        int slot = (shalf * 4 + jj) ^ (srow & 7);
        av[jj] = *(const f32x4*)(base + slot * 16);
      }
      const float* pf = (const float*)av;
      #pragma unroll
      for (int half = 0; half < 2; ++half) {
        u32x4 wa;
        #pragma unroll
        for (int e2 = 0; e2 < 4; ++e2)
          wa[e2] = cvtpk(pf[half * 8 + 2 * e2], pf[half * 8 + 2 * e2 + 1]);
        *(u32x4*)(abf + wbyte + ((shalf * 32 + half * 16) ^ sw)) = wa;
      }
    }
    asm volatile("s_waitcnt lgkmcnt(0)" ::: "memory");
    __builtin_amdgcn_sched_barrier(0);
    asm volatile("s_barrier" ::: "memory");

    s16x8 afr[4], bfr[4];
    #pragma unroll
    for (int mi = 0; mi < 4; ++mi) {
      int row = wr * 64 + mi * 16 + q15;
      afr[mi] = *(const s16x8*)(abf + row * 64 + ((g * 16) ^ ((row & 3) << 4)));
    }
    #pragma unroll
    for (int ni = 0; ni < 4; ++ni) {
      int row = wc * 64 + ni * 16 + q15;
      bfr[ni] = *(const s16x8*)(bbf + cur * 8192 + row * 64 + ((g * 16) ^ ((row & 3) << 4)));
    }
    #pragma unroll
    for (int mi = 0; mi < 4; ++mi)
      #pragma unroll
      for (int ni = 0; ni < 4; ++ni)
        acc[mi][ni] = mfma_bf16(afr[mi], bfr[ni], acc[mi][ni]);
  }

  float bias[4];
  #pragma unroll
  for (int ni = 0; ni < 4; ++ni) bias[ni] = Bv[n0 + wc * 64 + ni * 16 + q15];

  if (z < 2) {
    u16* Out = z ? Ko : Qo;
    const float scale = z ? 1.0f : 0.18033688011112042f;  // 1/8 * log2(e)
    #pragma unroll
    for (int mi = 0; mi < 4; ++mi)
      #pragma unroll
      for (int ni = 0; ni < 4; ++ni)
        #pragma unroll
        for (int r = 0; r < 4; r += 2) {
          int m = m0 + wr * 64 + mi * 16 + g * 4 + r;
          int n = n0 + wc * 64 + ni * 16 + q15;
          u32 pk = cvtpk((acc[mi][ni][r] + bias[ni]) * scale,
                         (acc[mi][ni][r + 1] + bias[ni]) * scale);
          Out[(size_t)m * 512 + n]       = (u16)pk;
          Out[(size_t)(m + 1) * 512 + n] = (u16)(pk >> 16);
        }
  } else {
    __syncthreads();
    #pragma unroll
    for (int mi = 0; mi < 4; ++mi)
      #pragma unroll
      for (int ni = 0; ni < 4; ++ni)
        #pragma unroll
        for (int r = 0; r < 4; r += 2) {
          int ml = wr * 64 + mi * 16 + g * 4 + r;
          int nl = wc * 64 + ni * 16 + q15;
          *(u32*)(smem + nl * 272 + ml * 2) =
              cvtpk(acc[mi][ni][r] + bias[ni], acc[mi][ni][r + 1] + bias[ni]);
        }
    __syncthreads();
    const int b  = m0 >> 11;
    const int s0 = m0 & 2047;
    #pragma unroll
    for (int nn = 0; nn < 2; ++nn) {
      int n  = nn * 64 + (t >> 2);
      int q4 = t & 3;
      u16* dst = VTo + (size_t)(b * 512 + n0 + n) * 2048 + s0 + q4 * 32;
      #pragma unroll
      for (int jj = 0; jj < 4; ++jj)
        *(s16x8*)(dst + jj * 8) = *(const s16x8*)(smem + n * 272 + q4 * 64 + jj * 16);
    }
  }
}

// ---------------------------------------------------------------------------
// Kernel 2: fused flash attention, KVBLK=128, compact u64 keep-bit masks
// (R12 body — empirical optimum at 112.8 us) + b-FASTEST block decode
// (R14-verified: XCD = bid%8 = b co-locates all (h,qt) blocks of a batch on
// one XCD -> K/VT and mask words L2-shared instead of HBM-refetched).
// grid.x = b + 8*h + 64*qt; block 256 = 4 waves x 32 q-rows.
// ---------------------------------------------------------------------------
__global__ __launch_bounds__(256, 2)
void attn_fwd(const u16* __restrict__ Q, const u16* __restrict__ K,
              const u16* __restrict__ VT, const u64* __restrict__ MP,
              float* __restrict__ out)
{
  __shared__ __align__(16) char lds_k[2][16384];    // [kv 128][d 64] bf16
  __shared__ __align__(16) char lds_v[2][2][8192];  // [buf][kvhalf][d64][kv64]

  const int bid = blockIdx.x;
  const int b = bid & 7, hh = (bid >> 3) & 7, qt = bid >> 6;   // b fastest
  const int t = threadIdx.x, lane = t & 63, w = t >> 6;
  const int l31 = lane & 31, hi = lane >> 5;
  const int qbase = qt * 128 + w * 32;
  const int swz = (l31 & 7) << 4;

  // Q B-frags (pre-scaled by 0.125*log2e): col=q=l31, k(d) = j*16 + 8*hi + e
  s16x8 qf[4];
  #pragma unroll
  for (int j = 0; j < 4; ++j)
    qf[j] = *(const s16x8*)(Q + (size_t)(b * 2048 + qbase + l31) * 512
                              + hh * 64 + j * 16 + hi * 8);
  asm volatile("" ::: "memory");

  f32x16 o0 = {0.f,0.f,0.f,0.f,0.f,0.f,0.f,0.f,0.f,0.f,0.f,0.f,0.f,0.f,0.f,0.f};
  f32x16 o1 = o0, o2 = o0;
  const f32x16 ZZ = o0;
  const s16x8 onesf = {0x3F80,0x3F80,0x3F80,0x3F80,0x3F80,0x3F80,0x3F80,0x3F80};

  const int srow8 = lane >> 3, slot = lane & 7;

  // K staging: instr i=0..3, rows rl = w*32 + i*8 + srow8 (0..127)
  const u16* kP[4];
  int kD[4];
  #pragma unroll
  for (int i = 0; i < 4; ++i) {
    int rl = w * 32 + i * 8 + srow8;
    kP[i] = K + (size_t)(b * 2048 + rl) * 512 + hh * 64 + (slot ^ (rl & 7)) * 8;
    kD[i] = (w * 32 + i * 8) * 128;
  }
  // V staging: instr i=0..1 per half, d = w*16 + i*8 + srow8 (0..63)
  const u16* vP[2];
  int vD[2];
  #pragma unroll
  for (int i = 0; i < 2; ++i) {
    int d = w * 16 + i * 8 + srow8;
    vP[i] = VT + (size_t)(b * 512 + hh * 64 + d) * 2048 + (slot ^ (d & 7)) * 8;
    vD[i] = (w * 16 + i * 8) * 128;
  }
  const u64* mpP = MP + (size_t)b * 32 * 2048 + qbase + l31;

  // prologue: stage tile 0 (kv 0..127) into buf 0; prefetch mask words 0,1
  #pragma unroll
  for (int i = 0; i < 4; ++i) gload_lds16(kP[i], &lds_k[0][kD[i]]);
  #pragma unroll
  for (int hf = 0; hf < 2; ++hf)
    #pragma unroll
    for (int i = 0; i < 2; ++i)
      gload_lds16(vP[i] + hf * 64, &lds_v[0][hf][vD[i]]);
  asm volatile("" ::: "memory");
  u64 pm0 = mpP[0], pm1 = mpP[2048];

  // one 64-kv half: QK (8 mfma) -> masked exp2/pack -> PV + ones (12 mfma)
#define HALF(KB, VB, KW) do {                                                  \
    f32x16 p0 = ZZ, p1 = ZZ;                                                   \
    _Pragma("unroll")                                                          \
    for (int j = 0; j < 4; ++j) {                                              \
      s16x8 a0 = *(const s16x8*)((KB) + l31 * 128        + ((j * 32 + hi * 16) ^ swz)); \
      s16x8 a1 = *(const s16x8*)((KB) + (l31 + 32) * 128 + ((j * 32 + hi * 16) ^ swz)); \
      p0 = mfma32(a0, qf[j], p0);                                              \
      p1 = mfma32(a1, qf[j], p1);                                              \
    }                                                                          \
    u64 kws = (KW) >> (hi * 4);                                                \
    u32 mm0 = (u32)kws, mm1 = (u32)(kws >> 32);                                \
    u32 wds[16];                                                               \
    _Pragma("unroll")                                                          \
    for (int t2 = 0; t2 < 2; ++t2) {                                           \
      const u32 mmw = t2 ? mm1 : mm0;                                          \
      _Pragma("unroll")                                                        \
      for (int q2 = 0; q2 < 8; ++q2) {                                         \
        const int bp = 8 * (q2 >> 1) + 2 * (q2 & 1);                           \
        float s0v = t2 ? p1[2 * q2] : p0[2 * q2];                              \
        float s1v = t2 ? p1[2 * q2 + 1] : p0[2 * q2 + 1];                      \
        float e0 = EXP2(s0v), e1 = EXP2(s1v);                                  \
        u32 k0 = (u32)((int)(mmw << (31 - bp)) >> 31);                         \
        u32 k1 = (u32)((int)(mmw << (30 - bp)) >> 31);                         \
        e0 = __builtin_bit_cast(float, __builtin_bit_cast(u32, e0) & k0);      \
        e1 = __builtin_bit_cast(float, __builtin_bit_cast(u32, e1) & k1);      \
        wds[t2 * 8 + q2] = cvtpk(e0, e1);                                      \
      }                                                                        \
    }                                                                          \
    _Pragma("unroll")                                                          \
    for (int j = 0; j < 4; ++j) {                                              \
      const int ia = 2 * j, ib = 2 * j + 1;                                    \
      u32 wa0 = wds[(ia >> 2) * 8 + 2 * (ia & 3)];                             \
      u32 wa1 = wds[(ia >> 2) * 8 + 2 * (ia & 3) + 1];                         \
      u32 wb0 = wds[(ib >> 2) * 8 + 2 * (ib & 3)];                             \
      u32 wb1 = wds[(ib >> 2) * 8 + 2 * (ib & 3) + 1];                         \
      asm("v_permlane32_swap_b32 %0, %1" : "+v"(wa0), "+v"(wb0));              \
      asm("v_permlane32_swap_b32 %0, %1" : "+v"(wa1), "+v"(wb1));              \
      u32x4 aw = {wa0, wa1, wb0, wb1};                                         \
      s16x8 af = __builtin_bit_cast(s16x8, aw);                                \
      s16x8 v0 = *(const s16x8*)((VB) + l31 * 128        + ((j * 32 + hi * 16) ^ swz)); \
      s16x8 v1 = *(const s16x8*)((VB) + (l31 + 32) * 128 + ((j * 32 + hi * 16) ^ swz)); \
      o0 = mfma32(af, v0, o0);                                                 \
      o1 = mfma32(af, v1, o1);                                                 \
      o2 = mfma32(af, onesf, o2);                                              \
    }                                                                          \
  } while (0)

  #pragma unroll 1
  for (int kt = 0; kt < 16; ++kt) {
    const int cur = kt & 1;
    const u64 kwA = pm0, kwB = pm1;
    if (kt + 1 < 16) {
      #pragma unroll
      for (int i = 0; i < 4; ++i) kP[i] += 65536;
      #pragma unroll
      for (int i = 0; i < 2; ++i) vP[i] += 128;
      mpP += 4096;
      #pragma unroll
      for (int i = 0; i < 4; ++i) gload_lds16(kP[i], &lds_k[cur ^ 1][kD[i]]);
      #pragma unroll
      for (int hf = 0; hf < 2; ++hf)
        #pragma unroll
        for (int i = 0; i < 2; ++i)
          gload_lds16(vP[i] + hf * 64, &lds_v[cur ^ 1][hf][vD[i]]);
      asm volatile("" ::: "memory");
      pm0 = mpP[0]; pm1 = mpP[2048];
      // newer than stage(kt): stage(kt+1)=8 + mask(kt+1)=2 = 10
      asm volatile("s_waitcnt vmcnt(10)" ::: "memory");
    } else {
      asm volatile("s_waitcnt vmcnt(0)" ::: "memory");
    }
    asm volatile("s_barrier" ::: "memory");

    HALF(&lds_k[cur][0],    &lds_v[cur][0][0], kwA);
    HALF(&lds_k[cur][8192], &lds_v[cur][1][0], kwB);

    asm volatile("s_waitcnt lgkmcnt(0)" ::: "memory");
    __builtin_amdgcn_sched_barrier(0);
    asm volatile("s_barrier" ::: "memory");
  }
#undef HALF

  // ---- epilogue: o2[reg] IS the row denominator for o0/o1[reg] ----
  #pragma unroll
  for (int reg = 0; reg < 16; ++reg) {
    const int ql = (reg & 3) + 8 * (reg >> 2) + 4 * hi;
    const float linv = 1.0f / o2[reg];
    float* po = out + (size_t)(b * 2048 + qbase + ql) * 512 + hh * 64 + l31;
    po[0]  = o0[reg] * linv;
    po[32] = o1[reg] * linv;
  }
}

extern "C" void kernel_launch(void* const* d_in, const int* in_sizes, int n_in,
                              void* d_out, int out_size, void* d_ws, size_t ws_size,
                              hipStream_t stream) {
  const float* xq  = (const float*)d_in[0];
  const float* xkv = (const float*)d_in[1];
  const int*   msk = (const int*)d_in[2];
  const float* wq  = (const float*)d_in[3];
  const float* bq  = (const float*)d_in[4];
  const float* wk  = (const float*)d_in[5];
  const float* bk  = (const float*)d_in[6];
  const float* wv  = (const float*)d_in[7];
  const float* bv  = (const float*)d_in[8];

  u16* Qw  = (u16*)d_ws;                         // [16384][512] bf16 (x 0.1803)
  u16* Kw  = Qw + (size_t)16384 * 512;           // [16384][512] bf16
  u16* VT  = Kw + (size_t)16384 * 512;           // [4096][2048] bf16 (V^T)
  u64* MP  = (u64*)(VT + (size_t)4096 * 2048);   // [8][32][2048] packed keep bits
  u16* Wbf = (u16*)(MP + (size_t)8 * 32 * 2048); // [3][512][512] bf16 weights

  mask_pack<<<dim3(8384), 256, 0, stream>>>(msk, MP, wq, wk, wv, Wbf);
  qkv_proj<<<dim3(128, 4, 3), 256, 0, stream>>>(xq, xkv, Wbf, bq, bk, bv,
                                                Qw, Kw, VT);
  attn_fwd<<<dim3(1024), 256, 0, stream>>>(Qw, Kw, VT, MP, (float*)d_out);
}

// Round 16
// 188.723 us; speedup vs baseline: 1.1901x; 1.0270x over previous
//
#include <hip/hip_runtime.h>
#include <hip/hip_bf16.h>
#include <math.h>

typedef float  f32x4  __attribute__((ext_vector_type(4)));
typedef float  f32x16 __attribute__((ext_vector_type(16)));
typedef short  s16x8  __attribute__((ext_vector_type(8)));
typedef __bf16 bf16x8 __attribute__((ext_vector_type(8)));
typedef unsigned int u32;
typedef unsigned int u32x4 __attribute__((ext_vector_type(4)));
typedef unsigned short u16;
typedef unsigned long long u64;

#define DEVI static __device__ __forceinline__

#if defined(__has_builtin) && __has_builtin(__builtin_amdgcn_exp2f)
#define EXP2(x) __builtin_amdgcn_exp2f(x)
#else
#define EXP2(x) exp2f(x)
#endif

// one-instruction packed f32->bf16 RNE pair (v_cvt_pk_bf16_f32)
DEVI u32 cvtpk(float lo, float hi) {
  u32 r;
  asm("v_cvt_pk_bf16_f32 %0, %1, %2" : "=v"(r) : "v"(lo), "v"(hi));
  return r;
}

DEVI f32x4 mfma_bf16(s16x8 a, s16x8 b, f32x4 c) {
  return __builtin_amdgcn_mfma_f32_16x16x32_bf16(
      __builtin_bit_cast(bf16x8, a), __builtin_bit_cast(bf16x8, b), c, 0, 0, 0);
}

DEVI f32x16 mfma32(s16x8 a, s16x8 b, f32x16 c) {
  return __builtin_amdgcn_mfma_f32_32x32x16_bf16(
      __builtin_bit_cast(bf16x8, a), __builtin_bit_cast(bf16x8, b), c, 0, 0, 0);
}

DEVI void gload_lds16(const void* g, void* l) {
  __builtin_amdgcn_global_load_lds(
      (const __attribute__((address_space(1))) void*)g,
      (__attribute__((address_space(3))) void*)l, 16, 0, 0);
}

// ---------------------------------------------------------------------------
// Kernel 0: blocks < 8192: bit-pack KEEP bits (16 words/wave, 2-deep ahead).
//           blocks >= 8192 (192): cast W{q,k,v} fp32 -> bf16 into Wbf.
// word (b,kt,q): bit l == 1  iff  kv = kt*64+l is KEPT (mask == 0).
// ---------------------------------------------------------------------------
__global__ __launch_bounds__(256)
void mask_pack(const int* __restrict__ mask, u64* __restrict__ mp,
               const float* __restrict__ wq, const float* __restrict__ wk,
               const float* __restrict__ wv, u16* __restrict__ Wbf) {
  const int t = threadIdx.x, lane = t & 63;
  if (blockIdx.x >= 8192) {             // ---- W cast: 192 blocks x 4096 elems
    const u32 blk = blockIdx.x - 8192;
    const u32 g0 = blk * 4096 + (u32)t * 16;
    const u32 mtx = g0 >> 18;           // 64 blocks per matrix
    const float* src = (mtx == 0) ? wq : (mtx == 1 ? wk : wv);
    const u32 idx = g0 & 262143u;
    #pragma unroll
    for (int i = 0; i < 2; ++i) {
      f32x4 v0 = *(const f32x4*)(src + idx + i * 8);
      f32x4 v1 = *(const f32x4*)(src + idx + i * 8 + 4);
      u32x4 pk;
      pk[0] = cvtpk(v0[0], v0[1]); pk[1] = cvtpk(v0[2], v0[3]);
      pk[2] = cvtpk(v1[0], v1[1]); pk[3] = cvtpk(v1[2], v1[3]);
      *(u32x4*)(Wbf + (size_t)mtx * 262144 + idx + i * 8) = pk;
    }
    return;
  }
  const u32 gw = blockIdx.x * 4 + (t >> 6);
  const u32 W0 = gw * 16;
  #define MSRC(W) ((((size_t)((W) >> 16) * 2048 + ((W) & 2047u)) * 2048) \
                   + (((W) >> 11) & 31u) * 64 + lane)
  int c0 = mask[MSRC(W0)];
  int c1 = mask[MSRC(W0 + 1)];
  #pragma unroll 4
  for (u32 k = 0; k < 16; ++k) {
    u64 bits = __ballot(c0 == 0);
    if (lane == 0) mp[W0 + k] = bits;
    c0 = c1;
    if (k + 2 < 16) c1 = mask[MSRC(W0 + k + 2)];
  }
  #undef MSRC
}

// ---------------------------------------------------------------------------
// Kernel 1: QKV projections, async staging + DIRECT per-lane A conversion:
// each lane converts its own A-fragment from the staged fp32 tile (identical
// bf16 bits -> bit-identical output), removing the abf LDS round-trip and one
// barrier per iter (3 -> 2).  LDS 48K -> 3 blocks/CU.
// ---------------------------------------------------------------------------
__global__ __launch_bounds__(256, 3)
void qkv_proj(const float* __restrict__ xq, const float* __restrict__ xkv,
              const u16* __restrict__ Wbf,
              const float* __restrict__ bq, const float* __restrict__ bk,
              const float* __restrict__ bv,
              u16* __restrict__ Qo, u16* __restrict__ Ko, u16* __restrict__ VTo)
{
  __shared__ __align__(16) char smem[49152];
  char* a32 = smem;                     // 2 x 16384: fp32 A tiles
  char* bbf = smem + 32768;             // 2 x 8192:  bf16 B tiles

  const int t = threadIdx.x, lane = t & 63, w = t >> 6;
  const int z = blockIdx.z;
  const float* X  = (z == 0) ? xq : xkv;
  const u16*   W  = Wbf + (size_t)z * 262144;
  const float* Bv = (z == 0) ? bq : (z == 1 ? bk : bv);

  const int m0 = blockIdx.x * 128, n0 = blockIdx.y * 128;
  const int wr = w >> 1, wc = w & 1, g = lane >> 4, q15 = lane & 15;

  f32x4 acc[4][4];
  #pragma unroll
  for (int i = 0; i < 4; ++i)
    #pragma unroll
    for (int j = 0; j < 4; ++j) acc[i][j] = (f32x4){0.f, 0.f, 0.f, 0.f};

  // A staging: instr i, lane -> chunk c = w*256+i*64+lane; r=c>>3, s=c&7,
  // source col-chunk j = s ^ (r&7)  (16B chunks of 4 floats)
  const float* aSrc[4];
  int aDst[4];
  #pragma unroll
  for (int i = 0; i < 4; ++i) {
    int c = w * 256 + i * 64 + lane;
    int r = c >> 3, s = c & 7, j = s ^ (r & 7);
    aSrc[i] = X + (size_t)(m0 + r) * 512 + j * 4;
    aDst[i] = (w * 256 + i * 64) * 16;
  }
  // B staging: instr i, chunk c = i*256+w*64+lane; r=c>>2, s=c&3, j=s^(r&3)
  const u16* bSrc[2];
  int bDst[2];
  #pragma unroll
  for (int i = 0; i < 2; ++i) {
    int c = i * 256 + w * 64 + lane;
    int r = c >> 2, s = c & 3, j = s ^ (r & 3);
    bSrc[i] = W + (size_t)(n0 + r) * 512 + j * 8;
    bDst[i] = (i * 256 + w * 64) * 16;
  }

  // prologue: stage tile 0 into buf 0
  #pragma unroll
  for (int i = 0; i < 4; ++i) gload_lds16(aSrc[i], a32 + aDst[i]);
  #pragma unroll
  for (int i = 0; i < 2; ++i) gload_lds16(bSrc[i], bbf + bDst[i]);
  asm volatile("" ::: "memory");

  #pragma unroll 1
  for (int kt = 0; kt < 16; ++kt) {
    const int cur = kt & 1;
    if (kt + 1 < 16) {
      #pragma unroll
      for (int i = 0; i < 4; ++i) {
        aSrc[i] += 32;
        gload_lds16(aSrc[i], a32 + (cur ^ 1) * 16384 + aDst[i]);
      }
      #pragma unroll
      for (int i = 0; i < 2; ++i) {
        bSrc[i] += 32;
        gload_lds16(bSrc[i], bbf + (cur ^ 1) * 8192 + bDst[i]);
      }
      asm volatile("" ::: "memory");
      // stage(kt) done; 6 newer (stage kt+1) stay in flight
      asm volatile("s_waitcnt vmcnt(6)" ::: "memory");
    } else {
      asm volatile("s_waitcnt vmcnt(0)" ::: "memory");
    }
    asm volatile("s_barrier" ::: "memory");   // stage(kt) visible to all waves

    // ---- per-lane A frag: read own fp32 chunks, convert (same bits as ever)
    s16x8 afr[4], bfr[4];
    const char* abase = a32 + cur * 16384;
    #pragma unroll
    for (int mi = 0; mi < 4; ++mi) {
      int row = wr * 64 + mi * 16 + q15;
      f32x4 lo = *(const f32x4*)(abase + row * 128 + (((2 * g)     ^ (row & 7)) * 16));
      f32x4 hi = *(const f32x4*)(abase + row * 128 + (((2 * g + 1) ^ (row & 7)) * 16));
      u32x4 pk;
      pk[0] = cvtpk(lo[0], lo[1]); pk[1] = cvtpk(lo[2], lo[3]);
      pk[2] = cvtpk(hi[0], hi[1]); pk[3] = cvtpk(hi[2], hi[3]);
      afr[mi] = __builtin_bit_cast(s16x8, pk);
    }
    #pragma unroll
    for (int ni = 0; ni < 4; ++ni) {
      int row = wc * 64 + ni * 16 + q15;
      bfr[ni] = *(const s16x8*)(bbf + cur * 8192 + row * 64 + ((g * 16) ^ ((row & 3) << 4)));
    }
    #pragma unroll
    for (int mi = 0; mi < 4; ++mi)
      #pragma unroll
      for (int ni = 0; ni < 4; ++ni)
        acc[mi][ni] = mfma_bf16(afr[mi], bfr[ni], acc[mi][ni]);

    asm volatile("s_waitcnt lgkmcnt(0)" ::: "memory");
    __builtin_amdgcn_sched_barrier(0);
    asm volatile("s_barrier" ::: "memory");   // reads done before next overwrite
  }

  float bias[4];
  #pragma unroll
  for (int ni = 0; ni < 4; ++ni) bias[ni] = Bv[n0 + wc * 64 + ni * 16 + q15];

  if (z < 2) {
    u16* Out = z ? Ko : Qo;
    const float scale = z ? 1.0f : 0.18033688011112042f;  // 1/8 * log2(e)
    #pragma unroll
    for (int mi = 0; mi < 4; ++mi)
      #pragma unroll
      for (int ni = 0; ni < 4; ++ni)
        #pragma unroll
        for (int r = 0; r < 4; r += 2) {
          int m = m0 + wr * 64 + mi * 16 + g * 4 + r;
          int n = n0 + wc * 64 + ni * 16 + q15;
          u32 pk = cvtpk((acc[mi][ni][r] + bias[ni]) * scale,
                         (acc[mi][ni][r + 1] + bias[ni]) * scale);
          Out[(size_t)m * 512 + n]       = (u16)pk;
          Out[(size_t)(m + 1) * 512 + n] = (u16)(pk >> 16);
        }
  } else {
    __syncthreads();                    // all frag reads done; reuse smem
    #pragma unroll
    for (int mi = 0; mi < 4; ++mi)
      #pragma unroll
      for (int ni = 0; ni < 4; ++ni)
        #pragma unroll
        for (int r = 0; r < 4; r += 2) {
          int ml = wr * 64 + mi * 16 + g * 4 + r;
          int nl = wc * 64 + ni * 16 + q15;
          *(u32*)(smem + nl * 272 + ml * 2) =
              cvtpk(acc[mi][ni][r] + bias[ni], acc[mi][ni][r + 1] + bias[ni]);
        }
    __syncthreads();
    const int b  = m0 >> 11;
    const int s0 = m0 & 2047;
    #pragma unroll
    for (int nn = 0; nn < 2; ++nn) {
      int n  = nn * 64 + (t >> 2);
      int q4 = t & 3;
      u16* dst = VTo + (size_t)(b * 512 + n0 + n) * 2048 + s0 + q4 * 32;
      #pragma unroll
      for (int jj = 0; jj < 4; ++jj)
        *(s16x8*)(dst + jj * 8) = *(const s16x8*)(smem + n * 272 + q4 * 64 + jj * 16);
    }
  }
}

// ---------------------------------------------------------------------------
// Kernel 2: fused flash attention (FROZEN, R15 form = empirical optimum):
// KVBLK=128, compact u64 keep-bit masks, b-fastest decode (XCD-coherent).
// grid.x = b + 8*h + 64*qt; block 256 = 4 waves x 32 q-rows.
// ---------------------------------------------------------------------------
__global__ __launch_bounds__(256, 2)
void attn_fwd(const u16* __restrict__ Q, const u16* __restrict__ K,
              const u16* __restrict__ VT, const u64* __restrict__ MP,
              float* __restrict__ out)
{
  __shared__ __align__(16) char lds_k[2][16384];    // [kv 128][d 64] bf16
  __shared__ __align__(16) char lds_v[2][2][8192];  // [buf][kvhalf][d64][kv64]

  const int bid = blockIdx.x;
  const int b = bid & 7, hh = (bid >> 3) & 7, qt = bid >> 6;   // b fastest
  const int t = threadIdx.x, lane = t & 63, w = t >> 6;
  const int l31 = lane & 31, hi = lane >> 5;
  const int qbase = qt * 128 + w * 32;
  const int swz = (l31 & 7) << 4;

  // Q B-frags (pre-scaled by 0.125*log2e): col=q=l31, k(d) = j*16 + 8*hi + e
  s16x8 qf[4];
  #pragma unroll
  for (int j = 0; j < 4; ++j)
    qf[j] = *(const s16x8*)(Q + (size_t)(b * 2048 + qbase + l31) * 512
                              + hh * 64 + j * 16 + hi * 8);
  asm volatile("" ::: "memory");

  f32x16 o0 = {0.f,0.f,0.f,0.f,0.f,0.f,0.f,0.f,0.f,0.f,0.f,0.f,0.f,0.f,0.f,0.f};
  f32x16 o1 = o0, o2 = o0;
  const f32x16 ZZ = o0;
  const s16x8 onesf = {0x3F80,0x3F80,0x3F80,0x3F80,0x3F80,0x3F80,0x3F80,0x3F80};

  const int srow8 = lane >> 3, slot = lane & 7;

  // K staging: instr i=0..3, rows rl = w*32 + i*8 + srow8 (0..127)
  const u16* kP[4];
  int kD[4];
  #pragma unroll
  for (int i = 0; i < 4; ++i) {
    int rl = w * 32 + i * 8 + srow8;
    kP[i] = K + (size_t)(b * 2048 + rl) * 512 + hh * 64 + (slot ^ (rl & 7)) * 8;
    kD[i] = (w * 32 + i * 8) * 128;
  }
  // V staging: instr i=0..1 per half, d = w*16 + i*8 + srow8 (0..63)
  const u16* vP[2];
  int vD[2];
  #pragma unroll
  for (int i = 0; i < 2; ++i) {
    int d = w * 16 + i * 8 + srow8;
    vP[i] = VT + (size_t)(b * 512 + hh * 64 + d) * 2048 + (slot ^ (d & 7)) * 8;
    vD[i] = (w * 16 + i * 8) * 128;
  }
  const u64* mpP = MP + (size_t)b * 32 * 2048 + qbase + l31;

  // prologue: stage tile 0 (kv 0..127) into buf 0; prefetch mask words 0,1
  #pragma unroll
  for (int i = 0; i < 4; ++i) gload_lds16(kP[i], &lds_k[0][kD[i]]);
  #pragma unroll
  for (int hf = 0; hf < 2; ++hf)
    #pragma unroll
    for (int i = 0; i < 2; ++i)
      gload_lds16(vP[i] + hf * 64, &lds_v[0][hf][vD[i]]);
  asm volatile("" ::: "memory");
  u64 pm0 = mpP[0], pm1 = mpP[2048];

  // one 64-kv half: QK (8 mfma) -> masked exp2/pack -> PV + ones (12 mfma)
#define HALF(KB, VB, KW) do {                                                  \
    f32x16 p0 = ZZ, p1 = ZZ;                                                   \
    _Pragma("unroll")                                                          \
    for (int j = 0; j < 4; ++j) {                                              \
      s16x8 a0 = *(const s16x8*)((KB) + l31 * 128        + ((j * 32 + hi * 16) ^ swz)); \
      s16x8 a1 = *(const s16x8*)((KB) + (l31 + 32) * 128 + ((j * 32 + hi * 16) ^ swz)); \
      p0 = mfma32(a0, qf[j], p0);                                              \
      p1 = mfma32(a1, qf[j], p1);                                              \
    }                                                                          \
    u64 kws = (KW) >> (hi * 4);                                                \
    u32 mm0 = (u32)kws, mm1 = (u32)(kws >> 32);                                \
    u32 wds[16];                                                               \
    _Pragma("unroll")                                                          \
    for (int t2 = 0; t2 < 2; ++t2) {                                           \
      const u32 mmw = t2 ? mm1 : mm0;                                          \
      _Pragma("unroll")                                                        \
      for (int q2 = 0; q2 < 8; ++q2) {                                         \
        const int bp = 8 * (q2 >> 1) + 2 * (q2 & 1);                           \
        float s0v = t2 ? p1[2 * q2] : p0[2 * q2];                              \
        float s1v = t2 ? p1[2 * q2 + 1] : p0[2 * q2 + 1];                      \
        float e0 = EXP2(s0v), e1 = EXP2(s1v);                                  \
        u32 k0 = (u32)((int)(mmw << (31 - bp)) >> 31);                         \
        u32 k1 = (u32)((int)(mmw << (30 - bp)) >> 31);                         \
        e0 = __builtin_bit_cast(float, __builtin_bit_cast(u32, e0) & k0);      \
        e1 = __builtin_bit_cast(float, __builtin_bit_cast(u32, e1) & k1);      \
        wds[t2 * 8 + q2] = cvtpk(e0, e1);                                      \
      }                                                                        \
    }                                                                          \
    _Pragma("unroll")                                                          \
    for (int j = 0; j < 4; ++j) {                                              \
      const int ia = 2 * j, ib = 2 * j + 1;                                    \
      u32 wa0 = wds[(ia >> 2) * 8 + 2 * (ia & 3)];                             \
      u32 wa1 = wds[(ia >> 2) * 8 + 2 * (ia & 3) + 1];                         \
      u32 wb0 = wds[(ib >> 2) * 8 + 2 * (ib & 3)];                             \
      u32 wb1 = wds[(ib >> 2) * 8 + 2 * (ib & 3) + 1];                         \
      asm("v_permlane32_swap_b32 %0, %1" : "+v"(wa0), "+v"(wb0));              \
      asm("v_permlane32_swap_b32 %0, %1" : "+v"(wa1), "+v"(wb1));              \
      u32x4 aw = {wa0, wa1, wb0, wb1};                                         \
      s16x8 af = __builtin_bit_cast(s16x8, aw);                                \
      s16x8 v0 = *(const s16x8*)((VB) + l31 * 128        + ((j * 32 + hi * 16) ^ swz)); \
      s16x8 v1 = *(const s16x8*)((VB) + (l31 + 32) * 128 + ((j * 32 + hi * 16) ^ swz)); \
      o0 = mfma32(af, v0, o0);                                                 \
      o1 = mfma32(af, v1, o1);                                                 \
      o2 = mfma32(af, onesf, o2);                                              \
    }                                                                          \
  } while (0)

  #pragma unroll 1
  for (int kt = 0; kt < 16; ++kt) {
    const int cur = kt & 1;
    const u64 kwA = pm0, kwB = pm1;
    if (kt + 1 < 16) {
      #pragma unroll
      for (int i = 0; i < 4; ++i) kP[i] += 65536;
      #pragma unroll
      for (int i = 0; i < 2; ++i) vP[i] += 128;
      mpP += 4096;
      #pragma unroll
      for (int i = 0; i < 4; ++i) gload_lds16(kP[i], &lds_k[cur ^ 1][kD[i]]);
      #pragma unroll
      for (int hf = 0; hf < 2; ++hf)
        #pragma unroll
        for (int i = 0; i < 2; ++i)
          gload_lds16(vP[i] + hf * 64, &lds_v[cur ^ 1][hf][vD[i]]);
      asm volatile("" ::: "memory");
      pm0 = mpP[0]; pm1 = mpP[2048];
      // newer than stage(kt): stage(kt+1)=8 + mask(kt+1)=2 = 10
      asm volatile("s_waitcnt vmcnt(10)" ::: "memory");
    } else {
      asm volatile("s_waitcnt vmcnt(0)" ::: "memory");
    }
    asm volatile("s_barrier" ::: "memory");

    HALF(&lds_k[cur][0],    &lds_v[cur][0][0], kwA);
    HALF(&lds_k[cur][8192], &lds_v[cur][1][0], kwB);

    asm volatile("s_waitcnt lgkmcnt(0)" ::: "memory");
    __builtin_amdgcn_sched_barrier(0);
    asm volatile("s_barrier" ::: "memory");
  }
#undef HALF

  // ---- epilogue: o2[reg] IS the row denominator for o0/o1[reg] ----
  #pragma unroll
  for (int reg = 0; reg < 16; ++reg) {
    const int ql = (reg & 3) + 8 * (reg >> 2) + 4 * hi;
    const float linv = 1.0f / o2[reg];
    float* po = out + (size_t)(b * 2048 + qbase + ql) * 512 + hh * 64 + l31;
    po[0]  = o0[reg] * linv;
    po[32] = o1[reg] * linv;
  }
}

extern "C" void kernel_launch(void* const* d_in, const int* in_sizes, int n_in,
                              void* d_out, int out_size, void* d_ws, size_t ws_size,
                              hipStream_t stream) {
  const float* xq  = (const float*)d_in[0];
  const float* xkv = (const float*)d_in[1];
  const int*   msk = (const int*)d_in[2];
  const float* wq  = (const float*)d_in[3];
  const float* bq  = (const float*)d_in[4];
  const float* wk  = (const float*)d_in[5];
  const float* bk  = (const float*)d_in[6];
  const float* wv  = (const float*)d_in[7];
  const float* bv  = (const float*)d_in[8];

  u16* Qw  = (u16*)d_ws;                         // [16384][512] bf16 (x 0.1803)
  u16* Kw  = Qw + (size_t)16384 * 512;           // [16384][512] bf16
  u16* VT  = Kw + (size_t)16384 * 512;           // [4096][2048] bf16 (V^T)
  u64* MP  = (u64*)(VT + (size_t)4096 * 2048);   // [8][32][2048] packed keep bits
  u16* Wbf = (u16*)(MP + (size_t)8 * 32 * 2048); // [3][512][512] bf16 weights

  mask_pack<<<dim3(8384), 256, 0, stream>>>(msk, MP, wq, wk, wv, Wbf);
  qkv_proj<<<dim3(128, 4, 3), 256, 0, stream>>>(xq, xkv, Wbf, bq, bk, bv,
                                                Qw, Kw, VT);
  attn_fwd<<<dim3(1024), 256, 0, stream>>>(Qw, Kw, VT, MP, (float*)d_out);
}